// Round 1
// baseline (2156.976 us; speedup 1.0000x reference)
//
#include <hip/hip_runtime.h>

// GCN 3-layer forward, fp32.
//   deg[i] = 1 + #incoming edges; dinv = rsqrt(deg)
//   per layer: h = x@W ; agg = sum_{e: dst=i} h[src]*dinv[src]*dinv[dst] + h[i]*dinv[i]^2
//              out = agg + b ; ReLU on layers 0,1
// Round 1 strategy: atomic-scatter aggregation (baseline). Self-loop term fused
// into the GEMM epilogue so agg needs no separate zero-init.

#define FEAT 64

// ---------- degree ----------
__global__ void deg_init_kernel(float* __restrict__ deg, int n) {
    int i = blockIdx.x * blockDim.x + threadIdx.x;
    if (i < n) deg[i] = 1.0f;  // self-loop
}

__global__ void deg_count_kernel(const int* __restrict__ dst, float* __restrict__ deg, int E) {
    int e = blockIdx.x * blockDim.x + threadIdx.x;
    if (e < E) atomicAdd(&deg[dst[e]], 1.0f);
}

__global__ void dinv_kernel(const float* __restrict__ deg, float* __restrict__ dinv, int n) {
    int i = blockIdx.x * blockDim.x + threadIdx.x;
    if (i < n) dinv[i] = rsqrtf(deg[i]);  // deg >= 1 always (self-loops)
}

// ---------- GEMM h = X @ W, plus epilogue AGG = h * dinv(row)^2 ----------
// Block: 256 threads, 16 rows x 64 cols per block. W (16 KB) + X-tile (4 KB) in LDS.
__global__ __launch_bounds__(256) void gemm_init_kernel(
    const float* __restrict__ X, const float* __restrict__ W,
    const float* __restrict__ dinv, float* __restrict__ H,
    float* __restrict__ AGG, int n) {
    __shared__ float w_lds[FEAT * FEAT];   // [k][c]
    __shared__ float x_lds[16 * FEAT];     // [r][k]

    const int t = threadIdx.x;
    // Load W: 4096 floats / 256 threads = 4 float4 each, coalesced.
#pragma unroll
    for (int i = 0; i < 4; ++i) {
        int idx = (i * 256 + t) * 4;
        *(float4*)&w_lds[idx] = *(const float4*)&W[idx];
    }

    const int r  = t >> 4;        // 0..15 local row
    const int c4 = t & 15;        // 0..15 float4 column group
    const int row = blockIdx.x * 16 + r;

    if (row < n) {
        *(float4*)&x_lds[r * FEAT + c4 * 4] = *(const float4*)&X[row * FEAT + c4 * 4];
    }
    __syncthreads();
    if (row >= n) return;

    float4 acc = make_float4(0.f, 0.f, 0.f, 0.f);
#pragma unroll
    for (int k = 0; k < FEAT; ++k) {
        const float xv = x_lds[r * FEAT + k];              // broadcast across c4
        const float4 wv = *(const float4*)&w_lds[k * FEAT + c4 * 4];
        acc.x += xv * wv.x; acc.y += xv * wv.y;
        acc.z += xv * wv.z; acc.w += xv * wv.w;
    }

    const int off = row * FEAT + c4 * 4;
    *(float4*)&H[off] = acc;
    const float di = dinv[row];
    const float w2 = di * di;  // self-loop norm
    float4 ag = make_float4(acc.x * w2, acc.y * w2, acc.z * w2, acc.w * w2);
    *(float4*)&AGG[off] = ag;
}

// ---------- edge scatter: AGG[dst] += H[src] * dinv[src]*dinv[dst] ----------
// 16 threads per edge, float4 gather, 4 scalar atomics each.
__global__ __launch_bounds__(256) void edge_scatter_kernel(
    const int* __restrict__ src, const int* __restrict__ dst,
    const float* __restrict__ dinv, const float* __restrict__ H,
    float* __restrict__ AGG, int E) {
    int gid = blockIdx.x * 256 + threadIdx.x;
    int e = gid >> 4;
    if (e >= E) return;
    int f = (gid & 15) * 4;
    int s = src[e];
    int d = dst[e];
    float norm = dinv[s] * dinv[d];
    float4 h4 = *(const float4*)&H[s * FEAT + f];
    float* out = &AGG[d * FEAT + f];
    atomicAdd(out + 0, h4.x * norm);
    atomicAdd(out + 1, h4.y * norm);
    atomicAdd(out + 2, h4.z * norm);
    atomicAdd(out + 3, h4.w * norm);
}

// ---------- bias (+ optional ReLU), in place ----------
__global__ void bias_act_kernel(float* __restrict__ A, const float* __restrict__ b,
                                int total, int relu) {
    int i = blockIdx.x * blockDim.x + threadIdx.x;
    if (i < total) {
        float v = A[i] + b[i & (FEAT - 1)];
        A[i] = relu ? fmaxf(v, 0.0f) : v;
    }
}

extern "C" void kernel_launch(void* const* d_in, const int* in_sizes, int n_in,
                              void* d_out, int out_size, void* d_ws, size_t ws_size,
                              hipStream_t stream) {
    const float* x  = (const float*)d_in[0];
    const int*   ei = (const int*)d_in[1];
    const float* W0 = (const float*)d_in[2];
    const float* b0 = (const float*)d_in[3];
    const float* W1 = (const float*)d_in[4];
    const float* b1 = (const float*)d_in[5];
    const float* W2 = (const float*)d_in[6];
    const float* b2 = (const float*)d_in[7];
    float* out = (float*)d_out;

    const int N = in_sizes[0] / FEAT;   // 50000
    const int E = in_sizes[1] / 2;      // 800000
    const int* src = ei;
    const int* dst = ei + E;

    // workspace layout (floats)
    float* ws   = (float*)d_ws;
    float* deg  = ws;                 // N
    float* dinv = ws + N;             // N
    float* H    = ws + 2 * N;         // N*FEAT
    float* bufA = H + (size_t)N * FEAT;     // N*FEAT
    float* bufB = bufA + (size_t)N * FEAT;  // N*FEAT

    const int tB = 256;
    const int gN    = (N + tB - 1) / tB;
    const int gE    = (E + tB - 1) / tB;
    const int gEd   = ((E * 16) + tB - 1) / tB;   // 16 threads/edge
    const int gElem = (N * FEAT + tB - 1) / tB;
    const int gGemm = (N + 15) / 16;

    // degrees
    deg_init_kernel<<<gN, tB, 0, stream>>>(deg, N);
    deg_count_kernel<<<gE, tB, 0, stream>>>(dst, deg, E);
    dinv_kernel<<<gN, tB, 0, stream>>>(deg, dinv, N);

    // layer 0: x -> bufA
    gemm_init_kernel<<<gGemm, tB, 0, stream>>>(x, W0, dinv, H, bufA, N);
    edge_scatter_kernel<<<gEd, tB, 0, stream>>>(src, dst, dinv, H, bufA, E);
    bias_act_kernel<<<gElem, tB, 0, stream>>>(bufA, b0, N * FEAT, 1);

    // layer 1: bufA -> bufB
    gemm_init_kernel<<<gGemm, tB, 0, stream>>>(bufA, W1, dinv, H, bufB, N);
    edge_scatter_kernel<<<gEd, tB, 0, stream>>>(src, dst, dinv, H, bufB, E);
    bias_act_kernel<<<gElem, tB, 0, stream>>>(bufB, b1, N * FEAT, 1);

    // layer 2: bufB -> out
    gemm_init_kernel<<<gGemm, tB, 0, stream>>>(bufB, W2, dinv, H, out, N);
    edge_scatter_kernel<<<gEd, tB, 0, stream>>>(src, dst, dinv, H, out, E);
    bias_act_kernel<<<gElem, tB, 0, stream>>>(out, b2, N * FEAT, 0);
}

// Round 2
// 418.445 us; speedup vs baseline: 5.1547x; 5.1547x over previous
//
#include <hip/hip_runtime.h>

// GCN 3-layer forward, fp32 — Round 2: CSR pull aggregation (no feature atomics).
//   dinv[i] = rsqrt(1 + indeg(i))
//   Hs = (x@W) * dinv[row]           (source norm folded into GEMM epilogue)
//   out[d] = dinv[d]*(sum_{s in CSR(d)} Hs[s] + Hs[d]) + b   (+ ReLU layers 0,1)

#define FEAT 64

// ---------- CSR build ----------
__global__ void zero_cnt_kernel(int* __restrict__ cnt, int n) {
    int i = blockIdx.x * blockDim.x + threadIdx.x;
    if (i < n) cnt[i] = 0;
}

__global__ void deg_count_kernel(const int* __restrict__ dst, int* __restrict__ cnt, int E) {
    int e = blockIdx.x * blockDim.x + threadIdx.x;
    if (e < E) atomicAdd(&cnt[dst[e]], 1);
}

__global__ void dinv_kernel(const int* __restrict__ cnt, float* __restrict__ dinv, int n) {
    int i = blockIdx.x * blockDim.x + threadIdx.x;
    if (i < n) dinv[i] = rsqrtf((float)(cnt[i] + 1));  // +1 self-loop
}

// single-block exclusive scan over n counts -> rowptr[0..n], cursor copy.
__global__ __launch_bounds__(1024) void scan_kernel(const int* __restrict__ cnt,
                                                    int* __restrict__ rowptr,
                                                    int* __restrict__ cursor, int n) {
    __shared__ int buf[1024];
    __shared__ int carry;
    if (threadIdx.x == 0) carry = 0;
    __syncthreads();
    for (int base = 0; base < n; base += 1024) {
        int i = base + (int)threadIdx.x;
        int v = (i < n) ? cnt[i] : 0;
        buf[threadIdx.x] = v;
        __syncthreads();
        for (int off = 1; off < 1024; off <<= 1) {
            int t = (threadIdx.x >= off) ? buf[threadIdx.x - off] : 0;
            __syncthreads();
            buf[threadIdx.x] += t;
            __syncthreads();
        }
        int excl = buf[threadIdx.x] - v + carry;  // read carry BEFORE update
        if (i < n) { rowptr[i] = excl; cursor[i] = excl; }
        __syncthreads();
        if (threadIdx.x == 1023) carry += buf[1023];
        __syncthreads();
    }
    if (threadIdx.x == 0) rowptr[n] = carry;
}

__global__ void fill_kernel(const int* __restrict__ src, const int* __restrict__ dst,
                            int* __restrict__ cursor, int* __restrict__ col, int E) {
    int e = blockIdx.x * blockDim.x + threadIdx.x;
    if (e < E) {
        int pos = atomicAdd(&cursor[dst[e]], 1);
        col[pos] = src[e];
    }
}

// ---------- GEMM: Hs = (X @ W) * dinv[row].  In-place safe (X == Hs ok): each
// block stages its own 16 rows to LDS before any global write. ----------
__global__ __launch_bounds__(256) void gemm_scaled_kernel(
    const float* __restrict__ X, const float* __restrict__ W,
    const float* __restrict__ dinv, float* __restrict__ Hs, int n) {
    __shared__ float w_lds[FEAT * FEAT];   // [k][c]
    __shared__ float x_lds[16 * FEAT];     // [r][k]

    const int t = threadIdx.x;
#pragma unroll
    for (int i = 0; i < 4; ++i) {
        int idx = (i * 256 + t) * 4;
        *(float4*)&w_lds[idx] = *(const float4*)&W[idx];
    }

    const int r   = t >> 4;       // 0..15 local row
    const int c4  = t & 15;       // float4 column group
    const int row = blockIdx.x * 16 + r;

    if (row < n) {
        *(float4*)&x_lds[r * FEAT + c4 * 4] = *(const float4*)&X[(size_t)row * FEAT + c4 * 4];
    }
    __syncthreads();
    if (row >= n) return;

    float4 acc = make_float4(0.f, 0.f, 0.f, 0.f);
#pragma unroll
    for (int k = 0; k < FEAT; ++k) {
        const float xv = x_lds[r * FEAT + k];
        const float4 wv = *(const float4*)&w_lds[k * FEAT + c4 * 4];
        acc.x += xv * wv.x; acc.y += xv * wv.y;
        acc.z += xv * wv.z; acc.w += xv * wv.w;
    }

    const float di = dinv[row];
    float4 o = make_float4(acc.x * di, acc.y * di, acc.z * di, acc.w * di);
    *(float4*)&Hs[(size_t)row * FEAT + c4 * 4] = o;
}

// ---------- pull aggregation + bias + activation ----------
// 16 lanes per node, float4 per lane; one coalesced 256B gather per neighbor.
__global__ __launch_bounds__(256) void agg_kernel(
    const int* __restrict__ rowptr, const int* __restrict__ col,
    const float* __restrict__ dinv, const float* __restrict__ Hs,
    const float* __restrict__ bias, float* __restrict__ out, int n, int relu) {
    const int g    = blockIdx.x * 16 + (threadIdx.x >> 4);  // node
    const int lane = threadIdx.x & 15;
    if (g >= n) return;
    const int f = lane * 4;

    // self-loop term: dinv[d]*Hs[d] summed with neighbors then scaled by dinv[d]
    float4 acc = *(const float4*)&Hs[(size_t)g * FEAT + f];

    const int beg = rowptr[g], end = rowptr[g + 1];
    for (int p = beg; p < end; ++p) {
        const int s = col[p];
        const float4 h = *(const float4*)&Hs[(size_t)s * FEAT + f];
        acc.x += h.x; acc.y += h.y; acc.z += h.z; acc.w += h.w;
    }

    const float dd = dinv[g];
    const float4 bv = *(const float4*)&bias[f];
    float4 o = make_float4(acc.x * dd + bv.x, acc.y * dd + bv.y,
                           acc.z * dd + bv.z, acc.w * dd + bv.w);
    if (relu) {
        o.x = fmaxf(o.x, 0.f); o.y = fmaxf(o.y, 0.f);
        o.z = fmaxf(o.z, 0.f); o.w = fmaxf(o.w, 0.f);
    }
    *(float4*)&out[(size_t)g * FEAT + f] = o;
}

extern "C" void kernel_launch(void* const* d_in, const int* in_sizes, int n_in,
                              void* d_out, int out_size, void* d_ws, size_t ws_size,
                              hipStream_t stream) {
    const float* x  = (const float*)d_in[0];
    const int*   ei = (const int*)d_in[1];
    const float* W0 = (const float*)d_in[2];
    const float* b0 = (const float*)d_in[3];
    const float* W1 = (const float*)d_in[4];
    const float* b1 = (const float*)d_in[5];
    const float* W2 = (const float*)d_in[6];
    const float* b2 = (const float*)d_in[7];
    float* out = (float*)d_out;

    const int N = in_sizes[0] / FEAT;   // 50000
    const int E = in_sizes[1] / 2;      // 800000
    const int* src = ei;
    const int* dst = ei + E;

    // workspace layout
    char* w = (char*)d_ws;
    int*   cnt    = (int*)w;                 w += sizeof(int) * (size_t)N;
    int*   rowptr = (int*)w;                 w += sizeof(int) * (size_t)(N + 1);
    int*   cursor = (int*)w;                 w += sizeof(int) * (size_t)N;
    int*   col    = (int*)w;                 w += sizeof(int) * (size_t)E;
    float* dinv   = (float*)w;               w += sizeof(float) * (size_t)N;
    float* B1     = (float*)w;               w += sizeof(float) * (size_t)N * FEAT;
    float* B2     = (float*)w;               w += sizeof(float) * (size_t)N * FEAT;

    const int tB = 256;
    const int gN = (N + tB - 1) / tB;
    const int gE = (E + tB - 1) / tB;
    const int g16 = (N + 15) / 16;

    // CSR build (shared by all 3 layers)
    zero_cnt_kernel<<<gN, tB, 0, stream>>>(cnt, N);
    deg_count_kernel<<<gE, tB, 0, stream>>>(dst, cnt, E);
    dinv_kernel<<<gN, tB, 0, stream>>>(cnt, dinv, N);
    scan_kernel<<<1, 1024, 0, stream>>>(cnt, rowptr, cursor, N);
    fill_kernel<<<gE, tB, 0, stream>>>(src, dst, cursor, col, E);

    // layer 0: x -> B1(Hs) -> B2
    gemm_scaled_kernel<<<g16, tB, 0, stream>>>(x, W0, dinv, B1, N);
    agg_kernel<<<g16, tB, 0, stream>>>(rowptr, col, dinv, B1, b0, B2, N, 1);

    // layer 1: B2 -> B2(Hs, in place) -> B1
    gemm_scaled_kernel<<<g16, tB, 0, stream>>>(B2, W1, dinv, B2, N);
    agg_kernel<<<g16, tB, 0, stream>>>(rowptr, col, dinv, B2, b1, B1, N, 1);

    // layer 2: B1 -> B1(Hs, in place) -> out
    gemm_scaled_kernel<<<g16, tB, 0, stream>>>(B1, W2, dinv, B1, N);
    agg_kernel<<<g16, tB, 0, stream>>>(rowptr, col, dinv, B1, b2, out, N, 0);
}

// Round 3
// 343.091 us; speedup vs baseline: 6.2869x; 1.2196x over previous
//
#include <hip/hip_runtime.h>

// GCN 3-layer forward, fp32 — Round 3: parallel CSR scan.
//   dinv[i] = rsqrt(1 + indeg(i))
//   Hs = (x@W) * dinv[row]           (source norm folded into GEMM epilogue)
//   out[d] = dinv[d]*(sum_{s in CSR(d)} Hs[s] + Hs[d]) + b   (+ ReLU layers 0,1)

#define FEAT 64
#define SCAN_B 1024

// ---------- CSR build ----------
__global__ void zero_cnt_kernel(int* __restrict__ cnt, int n) {
    int i = blockIdx.x * blockDim.x + threadIdx.x;
    if (i < n) cnt[i] = 0;
}

__global__ void deg_count_kernel(const int* __restrict__ dst, int* __restrict__ cnt, int E) {
    int e = blockIdx.x * blockDim.x + threadIdx.x;
    if (e < E) atomicAdd(&cnt[dst[e]], 1);
}

__global__ void dinv_kernel(const int* __restrict__ cnt, float* __restrict__ dinv, int n) {
    int i = blockIdx.x * blockDim.x + threadIdx.x;
    if (i < n) dinv[i] = rsqrtf((float)(cnt[i] + 1));  // +1 self-loop
}

// Pass 1: per-block exclusive scan of 1024-chunk; chunk-local result -> rowptr,
// chunk total -> bsum[blockIdx].
__global__ __launch_bounds__(SCAN_B) void scan_partial_kernel(
    const int* __restrict__ cnt, int* __restrict__ rowptr,
    int* __restrict__ bsum, int n) {
    __shared__ int wsum[SCAN_B / 64 + 1];
    const int tid  = threadIdx.x;
    const int lane = tid & 63;
    const int wid  = tid >> 6;
    const int i = blockIdx.x * SCAN_B + tid;

    int v = (i < n) ? cnt[i] : 0;
    // wave-inclusive scan
    int incl = v;
#pragma unroll
    for (int off = 1; off < 64; off <<= 1) {
        int t = __shfl_up(incl, off, 64);
        if (lane >= off) incl += t;
    }
    if (lane == 63) wsum[wid] = incl;
    __syncthreads();
    if (tid == 0) {
        int run = 0;
#pragma unroll
        for (int w = 0; w < SCAN_B / 64; ++w) { int t = wsum[w]; wsum[w] = run; run += t; }
        wsum[SCAN_B / 64] = run;           // block total
        bsum[blockIdx.x] = run;
    }
    __syncthreads();
    if (i < n) rowptr[i] = incl - v + wsum[wid];   // chunk-local exclusive
}

// Pass 2: exclusive scan of block sums (tiny, serial).
__global__ void scan_sums_kernel(int* __restrict__ bsum, int nb) {
    if (threadIdx.x == 0 && blockIdx.x == 0) {
        int run = 0;
        for (int b = 0; b < nb; ++b) { int t = bsum[b]; bsum[b] = run; run += t; }
        bsum[nb] = run;   // grand total
    }
}

// Pass 3: add block offsets; write cursor copy and rowptr[n].
__global__ __launch_bounds__(SCAN_B) void scan_add_kernel(
    int* __restrict__ rowptr, int* __restrict__ cursor,
    const int* __restrict__ bsum, int n, int nb) {
    const int i = blockIdx.x * SCAN_B + (int)threadIdx.x;
    if (i < n) {
        int v = rowptr[i] + bsum[blockIdx.x];
        rowptr[i] = v;
        cursor[i] = v;
    }
    if (i == 0) rowptr[n] = bsum[nb];
}

__global__ void fill_kernel(const int* __restrict__ src, const int* __restrict__ dst,
                            int* __restrict__ cursor, int* __restrict__ col, int E) {
    int e = blockIdx.x * blockDim.x + threadIdx.x;
    if (e < E) {
        int pos = atomicAdd(&cursor[dst[e]], 1);
        col[pos] = src[e];
    }
}

// ---------- GEMM: Hs = (X @ W) * dinv[row].  In-place safe (X == Hs ok): each
// block reads only the 16 rows it writes, staged to LDS first. ----------
__global__ __launch_bounds__(256) void gemm_scaled_kernel(
    const float* __restrict__ X, const float* __restrict__ W,
    const float* __restrict__ dinv, float* __restrict__ Hs, int n) {
    __shared__ float w_lds[FEAT * FEAT];   // [k][c]
    __shared__ float x_lds[16 * FEAT];     // [r][k]

    const int t = threadIdx.x;
#pragma unroll
    for (int i = 0; i < 4; ++i) {
        int idx = (i * 256 + t) * 4;
        *(float4*)&w_lds[idx] = *(const float4*)&W[idx];
    }

    const int r   = t >> 4;       // 0..15 local row
    const int c4  = t & 15;       // float4 column group
    const int row = blockIdx.x * 16 + r;

    if (row < n) {
        *(float4*)&x_lds[r * FEAT + c4 * 4] = *(const float4*)&X[(size_t)row * FEAT + c4 * 4];
    }
    __syncthreads();
    if (row >= n) return;

    float4 acc = make_float4(0.f, 0.f, 0.f, 0.f);
#pragma unroll
    for (int k = 0; k < FEAT; ++k) {
        const float xv = x_lds[r * FEAT + k];
        const float4 wv = *(const float4*)&w_lds[k * FEAT + c4 * 4];
        acc.x += xv * wv.x; acc.y += xv * wv.y;
        acc.z += xv * wv.z; acc.w += xv * wv.w;
    }

    const float di = dinv[row];
    float4 o = make_float4(acc.x * di, acc.y * di, acc.z * di, acc.w * di);
    *(float4*)&Hs[(size_t)row * FEAT + c4 * 4] = o;
}

// ---------- pull aggregation + bias + activation ----------
// 16 lanes per node, float4 per lane; one coalesced 256B gather per neighbor.
__global__ __launch_bounds__(256) void agg_kernel(
    const int* __restrict__ rowptr, const int* __restrict__ col,
    const float* __restrict__ dinv, const float* __restrict__ Hs,
    const float* __restrict__ bias, float* __restrict__ out, int n, int relu) {
    const int g    = blockIdx.x * 16 + (threadIdx.x >> 4);  // node
    const int lane = threadIdx.x & 15;
    if (g >= n) return;
    const int f = lane * 4;

    float4 acc = *(const float4*)&Hs[(size_t)g * FEAT + f];   // self-loop term

    const int beg = rowptr[g], end = rowptr[g + 1];
    for (int p = beg; p < end; ++p) {
        const int s = col[p];
        const float4 h = *(const float4*)&Hs[(size_t)s * FEAT + f];
        acc.x += h.x; acc.y += h.y; acc.z += h.z; acc.w += h.w;
    }

    const float dd = dinv[g];
    const float4 bv = *(const float4*)&bias[f];
    float4 o = make_float4(acc.x * dd + bv.x, acc.y * dd + bv.y,
                           acc.z * dd + bv.z, acc.w * dd + bv.w);
    if (relu) {
        o.x = fmaxf(o.x, 0.f); o.y = fmaxf(o.y, 0.f);
        o.z = fmaxf(o.z, 0.f); o.w = fmaxf(o.w, 0.f);
    }
    *(float4*)&out[(size_t)g * FEAT + f] = o;
}

extern "C" void kernel_launch(void* const* d_in, const int* in_sizes, int n_in,
                              void* d_out, int out_size, void* d_ws, size_t ws_size,
                              hipStream_t stream) {
    const float* x  = (const float*)d_in[0];
    const int*   ei = (const int*)d_in[1];
    const float* W0 = (const float*)d_in[2];
    const float* b0 = (const float*)d_in[3];
    const float* W1 = (const float*)d_in[4];
    const float* b1 = (const float*)d_in[5];
    const float* W2 = (const float*)d_in[6];
    const float* b2 = (const float*)d_in[7];
    float* out = (float*)d_out;

    const int N = in_sizes[0] / FEAT;   // 50000
    const int E = in_sizes[1] / 2;      // 800000
    const int* src = ei;
    const int* dst = ei + E;

    const int nbScan = (N + SCAN_B - 1) / SCAN_B;

    // workspace layout
    char* w = (char*)d_ws;
    int*   cnt    = (int*)w;                 w += sizeof(int) * (size_t)N;
    int*   rowptr = (int*)w;                 w += sizeof(int) * (size_t)(N + 1);
    int*   cursor = (int*)w;                 w += sizeof(int) * (size_t)N;
    int*   bsum   = (int*)w;                 w += sizeof(int) * (size_t)(nbScan + 1);
    int*   col    = (int*)w;                 w += sizeof(int) * (size_t)E;
    float* dinv   = (float*)w;               w += sizeof(float) * (size_t)N;
    float* B1     = (float*)w;               w += sizeof(float) * (size_t)N * FEAT;
    float* B2     = (float*)w;               w += sizeof(float) * (size_t)N * FEAT;

    const int tB = 256;
    const int gN = (N + tB - 1) / tB;
    const int gE = (E + tB - 1) / tB;
    const int g16 = (N + 15) / 16;

    // CSR build (shared by all 3 layers)
    zero_cnt_kernel<<<gN, tB, 0, stream>>>(cnt, N);
    deg_count_kernel<<<gE, tB, 0, stream>>>(dst, cnt, E);
    dinv_kernel<<<gN, tB, 0, stream>>>(cnt, dinv, N);
    scan_partial_kernel<<<nbScan, SCAN_B, 0, stream>>>(cnt, rowptr, bsum, N);
    scan_sums_kernel<<<1, 64, 0, stream>>>(bsum, nbScan);
    scan_add_kernel<<<nbScan, SCAN_B, 0, stream>>>(rowptr, cursor, bsum, N, nbScan);
    fill_kernel<<<gE, tB, 0, stream>>>(src, dst, cursor, col, E);

    // layer 0: x -> B1(Hs) -> B2
    gemm_scaled_kernel<<<g16, tB, 0, stream>>>(x, W0, dinv, B1, N);
    agg_kernel<<<g16, tB, 0, stream>>>(rowptr, col, dinv, B1, b0, B2, N, 1);

    // layer 1: B2 -> B2(Hs, in place) -> B1
    gemm_scaled_kernel<<<g16, tB, 0, stream>>>(B2, W1, dinv, B2, N);
    agg_kernel<<<g16, tB, 0, stream>>>(rowptr, col, dinv, B2, b1, B1, N, 1);

    // layer 2: B1 -> B1(Hs, in place) -> out
    gemm_scaled_kernel<<<g16, tB, 0, stream>>>(B1, W2, dinv, B1, N);
    agg_kernel<<<g16, tB, 0, stream>>>(rowptr, col, dinv, B1, b2, out, N, 0);
}

// Round 4
// 325.702 us; speedup vs baseline: 6.6225x; 1.0534x over previous
//
#include <hip/hip_runtime.h>

// GCN 3-layer forward, fp32 — Round 4: MLP-unrolled pull aggregation.
//   dinv[i] = rsqrt(1 + indeg(i))
//   Hs = (x@W) * dinv[row]           (source norm folded into GEMM epilogue)
//   out[d] = dinv[d]*(sum_{s in CSR(d)} Hs[s] + Hs[d]) + b   (+ ReLU layers 0,1)

#define FEAT 64
#define SCAN_B 1024

// ---------- CSR build ----------
__global__ void zero_cnt_kernel(int* __restrict__ cnt, int n) {
    int i = blockIdx.x * blockDim.x + threadIdx.x;
    if (i < n) cnt[i] = 0;
}

__global__ void deg_count_kernel(const int* __restrict__ dst, int* __restrict__ cnt, int E) {
    int e = blockIdx.x * blockDim.x + threadIdx.x;
    if (e < E) atomicAdd(&cnt[dst[e]], 1);
}

__global__ void dinv_kernel(const int* __restrict__ cnt, float* __restrict__ dinv, int n) {
    int i = blockIdx.x * blockDim.x + threadIdx.x;
    if (i < n) dinv[i] = rsqrtf((float)(cnt[i] + 1));  // +1 self-loop
}

// Pass 1: per-block exclusive scan of 1024-chunk; chunk-local result -> rowptr,
// chunk total -> bsum[blockIdx].
__global__ __launch_bounds__(SCAN_B) void scan_partial_kernel(
    const int* __restrict__ cnt, int* __restrict__ rowptr,
    int* __restrict__ bsum, int n) {
    __shared__ int wsum[SCAN_B / 64 + 1];
    const int tid  = threadIdx.x;
    const int lane = tid & 63;
    const int wid  = tid >> 6;
    const int i = blockIdx.x * SCAN_B + tid;

    int v = (i < n) ? cnt[i] : 0;
    int incl = v;
#pragma unroll
    for (int off = 1; off < 64; off <<= 1) {
        int t = __shfl_up(incl, off, 64);
        if (lane >= off) incl += t;
    }
    if (lane == 63) wsum[wid] = incl;
    __syncthreads();
    if (tid == 0) {
        int run = 0;
#pragma unroll
        for (int w = 0; w < SCAN_B / 64; ++w) { int t = wsum[w]; wsum[w] = run; run += t; }
        wsum[SCAN_B / 64] = run;
        bsum[blockIdx.x] = run;
    }
    __syncthreads();
    if (i < n) rowptr[i] = incl - v + wsum[wid];
}

// Pass 2: exclusive scan of block sums (tiny, serial).
__global__ void scan_sums_kernel(int* __restrict__ bsum, int nb) {
    if (threadIdx.x == 0 && blockIdx.x == 0) {
        int run = 0;
        for (int b = 0; b < nb; ++b) { int t = bsum[b]; bsum[b] = run; run += t; }
        bsum[nb] = run;
    }
}

// Pass 3: add block offsets; write cursor copy and rowptr[n].
__global__ __launch_bounds__(SCAN_B) void scan_add_kernel(
    int* __restrict__ rowptr, int* __restrict__ cursor,
    const int* __restrict__ bsum, int n, int nb) {
    const int i = blockIdx.x * SCAN_B + (int)threadIdx.x;
    if (i < n) {
        int v = rowptr[i] + bsum[blockIdx.x];
        rowptr[i] = v;
        cursor[i] = v;
    }
    if (i == 0) rowptr[n] = bsum[nb];
}

__global__ void fill_kernel(const int* __restrict__ src, const int* __restrict__ dst,
                            int* __restrict__ cursor, int* __restrict__ col, int E) {
    int e = blockIdx.x * blockDim.x + threadIdx.x;
    if (e < E) {
        int pos = atomicAdd(&cursor[dst[e]], 1);
        col[pos] = src[e];
    }
}

// ---------- GEMM: Hs = (X @ W) * dinv[row].  In-place safe (X == Hs ok): each
// block reads only the 16 rows it writes, staged to LDS first. ----------
__global__ __launch_bounds__(256) void gemm_scaled_kernel(
    const float* __restrict__ X, const float* __restrict__ W,
    const float* __restrict__ dinv, float* __restrict__ Hs, int n) {
    __shared__ float w_lds[FEAT * FEAT];   // [k][c]
    __shared__ float x_lds[16 * FEAT];     // [r][k]

    const int t = threadIdx.x;
#pragma unroll
    for (int i = 0; i < 4; ++i) {
        int idx = (i * 256 + t) * 4;
        *(float4*)&w_lds[idx] = *(const float4*)&W[idx];
    }

    const int r   = t >> 4;
    const int c4  = t & 15;
    const int row = blockIdx.x * 16 + r;

    if (row < n) {
        *(float4*)&x_lds[r * FEAT + c4 * 4] = *(const float4*)&X[(size_t)row * FEAT + c4 * 4];
    }
    __syncthreads();
    if (row >= n) return;

    float4 acc = make_float4(0.f, 0.f, 0.f, 0.f);
#pragma unroll
    for (int k = 0; k < FEAT; ++k) {
        const float xv = x_lds[r * FEAT + k];
        const float4 wv = *(const float4*)&w_lds[k * FEAT + c4 * 4];
        acc.x += xv * wv.x; acc.y += xv * wv.y;
        acc.z += xv * wv.z; acc.w += xv * wv.w;
    }

    const float di = dinv[row];
    float4 o = make_float4(acc.x * di, acc.y * di, acc.z * di, acc.w * di);
    *(float4*)&Hs[(size_t)row * FEAT + c4 * 4] = o;
}

// ---------- pull aggregation + bias + activation ----------
// 16 lanes per node, float4 per lane; 4-way unrolled neighbor loop so 4
// 256B gathers are in flight per group (MLP), two accumulators to split
// the dependency chain.
__global__ __launch_bounds__(256) void agg_kernel(
    const int* __restrict__ rowptr, const int* __restrict__ col,
    const float* __restrict__ dinv, const float* __restrict__ Hs,
    const float* __restrict__ bias, float* __restrict__ out, int n, int relu) {
    const int g    = blockIdx.x * 16 + (threadIdx.x >> 4);  // node
    const int lane = threadIdx.x & 15;
    if (g >= n) return;
    const int f = lane * 4;
    const float* __restrict__ Hf = Hs + f;

    float4 a0 = *(const float4*)&Hf[(size_t)g * FEAT];   // self-loop term
    float4 a1 = make_float4(0.f, 0.f, 0.f, 0.f);

    int p = rowptr[g];
    const int end = rowptr[g + 1];

    for (; p + 4 <= end; p += 4) {
        const int s0 = col[p + 0];
        const int s1 = col[p + 1];
        const int s2 = col[p + 2];
        const int s3 = col[p + 3];
        const float4 h0 = *(const float4*)&Hf[(size_t)s0 * FEAT];
        const float4 h1 = *(const float4*)&Hf[(size_t)s1 * FEAT];
        const float4 h2 = *(const float4*)&Hf[(size_t)s2 * FEAT];
        const float4 h3 = *(const float4*)&Hf[(size_t)s3 * FEAT];
        a0.x += h0.x; a0.y += h0.y; a0.z += h0.z; a0.w += h0.w;
        a1.x += h1.x; a1.y += h1.y; a1.z += h1.z; a1.w += h1.w;
        a0.x += h2.x; a0.y += h2.y; a0.z += h2.z; a0.w += h2.w;
        a1.x += h3.x; a1.y += h3.y; a1.z += h3.z; a1.w += h3.w;
    }
    for (; p < end; ++p) {
        const int s = col[p];
        const float4 h = *(const float4*)&Hf[(size_t)s * FEAT];
        a0.x += h.x; a0.y += h.y; a0.z += h.z; a0.w += h.w;
    }

    const float dd = dinv[g];
    const float4 bv = *(const float4*)&bias[f];
    float4 o = make_float4((a0.x + a1.x) * dd + bv.x, (a0.y + a1.y) * dd + bv.y,
                           (a0.z + a1.z) * dd + bv.z, (a0.w + a1.w) * dd + bv.w);
    if (relu) {
        o.x = fmaxf(o.x, 0.f); o.y = fmaxf(o.y, 0.f);
        o.z = fmaxf(o.z, 0.f); o.w = fmaxf(o.w, 0.f);
    }
    *(float4*)&out[(size_t)g * FEAT + f] = o;
}

extern "C" void kernel_launch(void* const* d_in, const int* in_sizes, int n_in,
                              void* d_out, int out_size, void* d_ws, size_t ws_size,
                              hipStream_t stream) {
    const float* x  = (const float*)d_in[0];
    const int*   ei = (const int*)d_in[1];
    const float* W0 = (const float*)d_in[2];
    const float* b0 = (const float*)d_in[3];
    const float* W1 = (const float*)d_in[4];
    const float* b1 = (const float*)d_in[5];
    const float* W2 = (const float*)d_in[6];
    const float* b2 = (const float*)d_in[7];
    float* out = (float*)d_out;

    const int N = in_sizes[0] / FEAT;   // 50000
    const int E = in_sizes[1] / 2;      // 800000
    const int* src = ei;
    const int* dst = ei + E;

    const int nbScan = (N + SCAN_B - 1) / SCAN_B;

    // workspace layout
    char* w = (char*)d_ws;
    int*   cnt    = (int*)w;                 w += sizeof(int) * (size_t)N;
    int*   rowptr = (int*)w;                 w += sizeof(int) * (size_t)(N + 1);
    int*   cursor = (int*)w;                 w += sizeof(int) * (size_t)N;
    int*   bsum   = (int*)w;                 w += sizeof(int) * (size_t)(nbScan + 1);
    int*   col    = (int*)w;                 w += sizeof(int) * (size_t)E;
    float* dinv   = (float*)w;               w += sizeof(float) * (size_t)N;
    float* B1     = (float*)w;               w += sizeof(float) * (size_t)N * FEAT;
    float* B2     = (float*)w;               w += sizeof(float) * (size_t)N * FEAT;

    const int tB = 256;
    const int gN = (N + tB - 1) / tB;
    const int gE = (E + tB - 1) / tB;
    const int g16 = (N + 15) / 16;

    // CSR build (shared by all 3 layers)
    zero_cnt_kernel<<<gN, tB, 0, stream>>>(cnt, N);
    deg_count_kernel<<<gE, tB, 0, stream>>>(dst, cnt, E);
    dinv_kernel<<<gN, tB, 0, stream>>>(cnt, dinv, N);
    scan_partial_kernel<<<nbScan, SCAN_B, 0, stream>>>(cnt, rowptr, bsum, N);
    scan_sums_kernel<<<1, 64, 0, stream>>>(bsum, nbScan);
    scan_add_kernel<<<nbScan, SCAN_B, 0, stream>>>(rowptr, cursor, bsum, N, nbScan);
    fill_kernel<<<gE, tB, 0, stream>>>(src, dst, cursor, col, E);

    // layer 0: x -> B1(Hs) -> B2
    gemm_scaled_kernel<<<g16, tB, 0, stream>>>(x, W0, dinv, B1, N);
    agg_kernel<<<g16, tB, 0, stream>>>(rowptr, col, dinv, B1, b0, B2, N, 1);

    // layer 1: B2 -> B2(Hs, in place) -> B1
    gemm_scaled_kernel<<<g16, tB, 0, stream>>>(B2, W1, dinv, B2, N);
    agg_kernel<<<g16, tB, 0, stream>>>(rowptr, col, dinv, B2, b1, B1, N, 1);

    // layer 2: B1 -> B1(Hs, in place) -> out
    gemm_scaled_kernel<<<g16, tB, 0, stream>>>(B1, W2, dinv, B1, N);
    agg_kernel<<<g16, tB, 0, stream>>>(rowptr, col, dinv, B1, b2, out, N, 0);
}

// Round 5
// 260.095 us; speedup vs baseline: 8.2930x; 1.2522x over previous
//
#include <hip/hip_runtime.h>

// GCN 3-layer forward, fp32 — Round 5: linearity-fused layers + atomic-free fill.
//   agg(X@W) == agg(X)@W  (aggregation is linear)  =>  per layer:
//     S[d]  = sum_{s in CSR(d)} Xs[s] + Xs[d]        (Xs = X * dinv, prescaled)
//     T     = S @ W                                   (in-block LDS GEMM)
//     y     = relu(dinv[d]*T + b)                     (ReLU layers 0,1)
//     next-layer input = y * dinv[d]                  (folded into epilogue)
//   CSR: rank[e] = atomicAdd(cnt[dst],1) during degree count, then fill is
//   atomic-free: col[rowptr[dst]+rank] = src.

#define FEAT 64
#define SCAN_B 1024

// ---------- CSR build ----------
__global__ void zero_cnt_kernel(int* __restrict__ cnt, int n) {
    int i = blockIdx.x * blockDim.x + threadIdx.x;
    if (i < n) cnt[i] = 0;
}

// degree count; atomic return value = within-row rank of edge e.
__global__ void deg_rank_kernel(const int* __restrict__ dst, int* __restrict__ cnt,
                                int* __restrict__ rank, int E) {
    int e = blockIdx.x * blockDim.x + threadIdx.x;
    if (e < E) rank[e] = atomicAdd(&cnt[dst[e]], 1);
}

__global__ void dinv_kernel(const int* __restrict__ cnt, float* __restrict__ dinv, int n) {
    int i = blockIdx.x * blockDim.x + threadIdx.x;
    if (i < n) dinv[i] = rsqrtf((float)(cnt[i] + 1));  // +1 self-loop
}

// Pass 1: per-block exclusive scan of 1024-chunk -> rowptr (chunk-local), bsum.
__global__ __launch_bounds__(SCAN_B) void scan_partial_kernel(
    const int* __restrict__ cnt, int* __restrict__ rowptr,
    int* __restrict__ bsum, int n) {
    __shared__ int wsum[SCAN_B / 64 + 1];
    const int tid  = threadIdx.x;
    const int lane = tid & 63;
    const int wid  = tid >> 6;
    const int i = blockIdx.x * SCAN_B + tid;

    int v = (i < n) ? cnt[i] : 0;
    int incl = v;
#pragma unroll
    for (int off = 1; off < 64; off <<= 1) {
        int t = __shfl_up(incl, off, 64);
        if (lane >= off) incl += t;
    }
    if (lane == 63) wsum[wid] = incl;
    __syncthreads();
    if (tid == 0) {
        int run = 0;
#pragma unroll
        for (int w = 0; w < SCAN_B / 64; ++w) { int t = wsum[w]; wsum[w] = run; run += t; }
        wsum[SCAN_B / 64] = run;
        bsum[blockIdx.x] = run;
    }
    __syncthreads();
    if (i < n) rowptr[i] = incl - v + wsum[wid];
}

// Pass 2: exclusive scan of block sums (tiny, serial).
__global__ void scan_sums_kernel(int* __restrict__ bsum, int nb) {
    if (threadIdx.x == 0 && blockIdx.x == 0) {
        int run = 0;
        for (int b = 0; b < nb; ++b) { int t = bsum[b]; bsum[b] = run; run += t; }
        bsum[nb] = run;
    }
}

// Pass 3: add block offsets; write rowptr[n].
__global__ __launch_bounds__(SCAN_B) void scan_add_kernel(
    int* __restrict__ rowptr, const int* __restrict__ bsum, int n, int nb) {
    const int i = blockIdx.x * SCAN_B + (int)threadIdx.x;
    if (i < n) rowptr[i] += bsum[blockIdx.x];
    if (i == 0) rowptr[n] = bsum[nb];
}

// Atomic-free CSR fill.
__global__ void fill_kernel(const int* __restrict__ src, const int* __restrict__ dst,
                            const int* __restrict__ rank, const int* __restrict__ rowptr,
                            int* __restrict__ col, int E) {
    int e = blockIdx.x * blockDim.x + threadIdx.x;
    if (e < E) col[rowptr[dst[e]] + rank[e]] = src[e];
}

// Xs = x * dinv[row]   (i indexes float4s; 16 float4s per row)
__global__ void prescale_kernel(const float* __restrict__ x, const float* __restrict__ dinv,
                                float* __restrict__ xs, int nq) {
    int i = blockIdx.x * blockDim.x + threadIdx.x;
    if (i < nq) {
        float d = dinv[i >> 4];
        float4 v = ((const float4*)x)[i];
        ((float4*)xs)[i] = make_float4(v.x * d, v.y * d, v.z * d, v.w * d);
    }
}

// ---------- fused layer: gather-sum -> LDS -> GEMM -> bias/act ----------
// 16 nodes per block, 16 lanes per node (float4/lane). Aggregated rows are
// wave-private in LDS (wave w owns rows 4w..4w+3) so no barrier after the
// gather loop; the only barrier is after the W load at the top.
__global__ __launch_bounds__(256) void layer_kernel(
    const int* __restrict__ rowptr, const int* __restrict__ col,
    const float* __restrict__ dinv, const float* __restrict__ Xs,
    const float* __restrict__ W, const float* __restrict__ bias,
    float* __restrict__ out, int n, int inter) {
    __shared__ float w_lds[FEAT * FEAT];   // [k][c]
    __shared__ float s_tile[16 * FEAT];    // [r][k] aggregated sums

    const int t = threadIdx.x;
#pragma unroll
    for (int i = 0; i < 4; ++i) {
        int idx = (i * 256 + t) * 4;
        *(float4*)&w_lds[idx] = *(const float4*)&W[idx];
    }
    __syncthreads();   // W visible; nothing else needs a barrier below

    const int r  = t >> 4;       // local node 0..15
    const int c4 = t & 15;       // float4 feature group
    const int g  = blockIdx.x * 16 + r;
    if (g >= n) return;
    const int f = c4 * 4;
    const float* __restrict__ Hf = Xs + f;

    // gather raw sums (input is prescaled by dinv[src])
    float4 a0 = *(const float4*)&Hf[(size_t)g * FEAT];   // self-loop term
    float4 a1 = make_float4(0.f, 0.f, 0.f, 0.f);
    int p = rowptr[g];
    const int end = rowptr[g + 1];
    for (; p + 4 <= end; p += 4) {
        const int s0 = col[p + 0];
        const int s1 = col[p + 1];
        const int s2 = col[p + 2];
        const int s3 = col[p + 3];
        const float4 h0 = *(const float4*)&Hf[(size_t)s0 * FEAT];
        const float4 h1 = *(const float4*)&Hf[(size_t)s1 * FEAT];
        const float4 h2 = *(const float4*)&Hf[(size_t)s2 * FEAT];
        const float4 h3 = *(const float4*)&Hf[(size_t)s3 * FEAT];
        a0.x += h0.x; a0.y += h0.y; a0.z += h0.z; a0.w += h0.w;
        a1.x += h1.x; a1.y += h1.y; a1.z += h1.z; a1.w += h1.w;
        a0.x += h2.x; a0.y += h2.y; a0.z += h2.z; a0.w += h2.w;
        a1.x += h3.x; a1.y += h3.y; a1.z += h3.z; a1.w += h3.w;
    }
    for (; p < end; ++p) {
        const int s = col[p];
        const float4 h = *(const float4*)&Hf[(size_t)s * FEAT];
        a0.x += h.x; a0.y += h.y; a0.z += h.z; a0.w += h.w;
    }
    float4 S = make_float4(a0.x + a1.x, a0.y + a1.y, a0.z + a1.z, a0.w + a1.w);
    *(float4*)&s_tile[r * FEAT + f] = S;
    // no __syncthreads: wave w reads only rows 4w..4w+3, which it wrote

    // in-block GEMM: T[r][f..f+3] = sum_k S[r][k] * W[k][f..f+3]
    float4 acc = make_float4(0.f, 0.f, 0.f, 0.f);
#pragma unroll
    for (int k = 0; k < FEAT; ++k) {
        const float sv = s_tile[r * FEAT + k];
        const float4 wv = *(const float4*)&w_lds[k * FEAT + f];
        acc.x += sv * wv.x; acc.y += sv * wv.y;
        acc.z += sv * wv.z; acc.w += sv * wv.w;
    }

    const float dd = dinv[g];
    const float4 bv = *(const float4*)&bias[f];
    float4 o = make_float4(acc.x * dd + bv.x, acc.y * dd + bv.y,
                           acc.z * dd + bv.z, acc.w * dd + bv.w);
    if (inter) {   // ReLU, then pre-scale for next layer's gather
        o.x = fmaxf(o.x, 0.f) * dd; o.y = fmaxf(o.y, 0.f) * dd;
        o.z = fmaxf(o.z, 0.f) * dd; o.w = fmaxf(o.w, 0.f) * dd;
    }
    *(float4*)&out[(size_t)g * FEAT + f] = o;
}

extern "C" void kernel_launch(void* const* d_in, const int* in_sizes, int n_in,
                              void* d_out, int out_size, void* d_ws, size_t ws_size,
                              hipStream_t stream) {
    const float* x  = (const float*)d_in[0];
    const int*   ei = (const int*)d_in[1];
    const float* W0 = (const float*)d_in[2];
    const float* b0 = (const float*)d_in[3];
    const float* W1 = (const float*)d_in[4];
    const float* b1 = (const float*)d_in[5];
    const float* W2 = (const float*)d_in[6];
    const float* b2 = (const float*)d_in[7];
    float* out = (float*)d_out;

    const int N = in_sizes[0] / FEAT;   // 50000
    const int E = in_sizes[1] / 2;      // 800000
    const int* src = ei;
    const int* dst = ei + E;

    const int nbScan = (N + SCAN_B - 1) / SCAN_B;

    // workspace layout
    char* w = (char*)d_ws;
    int*   cnt    = (int*)w;                 w += sizeof(int) * (size_t)N;
    int*   rowptr = (int*)w;                 w += sizeof(int) * (size_t)(N + 1);
    int*   bsum   = (int*)w;                 w += sizeof(int) * (size_t)(nbScan + 1);
    int*   col    = (int*)w;                 w += sizeof(int) * (size_t)E;
    float* dinv   = (float*)w;               w += sizeof(float) * (size_t)N;
    float* B1     = (float*)w;               w += sizeof(float) * (size_t)N * FEAT;
    float* B2     = (float*)w;               w += sizeof(float) * (size_t)N * FEAT;
    int*   rank   = (int*)B2;   // alias: rank dead before layer0 writes B2

    const int tB = 256;
    const int gN = (N + tB - 1) / tB;
    const int gE = (E + tB - 1) / tB;
    const int g16 = (N + 15) / 16;
    const int nq = N * FEAT / 4;
    const int gQ = (nq + tB - 1) / tB;

    // CSR build (shared by all 3 layers)
    zero_cnt_kernel<<<gN, tB, 0, stream>>>(cnt, N);
    deg_rank_kernel<<<gE, tB, 0, stream>>>(dst, cnt, rank, E);
    dinv_kernel<<<gN, tB, 0, stream>>>(cnt, dinv, N);
    scan_partial_kernel<<<nbScan, SCAN_B, 0, stream>>>(cnt, rowptr, bsum, N);
    scan_sums_kernel<<<1, 64, 0, stream>>>(bsum, nbScan);
    scan_add_kernel<<<nbScan, SCAN_B, 0, stream>>>(rowptr, bsum, N, nbScan);
    fill_kernel<<<gE, tB, 0, stream>>>(src, dst, rank, rowptr, col, E);

    // prescale input: B1 = x * dinv[row]
    prescale_kernel<<<gQ, tB, 0, stream>>>(x, dinv, B1, nq);

    // fused layers
    layer_kernel<<<g16, tB, 0, stream>>>(rowptr, col, dinv, B1, W0, b0, B2, N, 1);
    layer_kernel<<<g16, tB, 0, stream>>>(rowptr, col, dinv, B2, W1, b1, B1, N, 1);
    layer_kernel<<<g16, tB, 0, stream>>>(rowptr, col, dinv, B1, W2, b2, out, N, 0);
}

// Round 6
// 253.761 us; speedup vs baseline: 8.5000x; 1.0250x over previous
//
#include <hip/hip_runtime.h>

// GCN 3-layer forward, fp32 — Round 6: segment-sorted CSR for gather locality.
//   agg(X@W) == agg(X)@W  =>  per layer: gather-sum -> in-block GEMM -> bias/act.
//   CSR keyed by v = dst*8 + (src>>13): node d's edges are [rowptr[8d],rowptr[8d+8]),
//   sorted by 8 KB-node source segment (2 MB of Xs each) => L2-resident gather window.
//   rank[e] = atomicAdd(cnt[v],1) makes the fill atomic-free.

#define FEAT 64
#define SCAN_B 1024
#define SEG 8
#define SEG_SHIFT 13   // src>>13: N<=65536 -> segment 0..7

// degree count over virtual rows; atomic return value = within-row rank.
__global__ void deg_rank_kernel(const int* __restrict__ src, const int* __restrict__ dst,
                                int* __restrict__ cnt, int* __restrict__ rank, int E4) {
    int i = blockIdx.x * blockDim.x + threadIdx.x;
    if (i < E4) {
        int4 s = ((const int4*)src)[i];
        int4 d = ((const int4*)dst)[i];
        int4 r;
        r.x = atomicAdd(&cnt[d.x * SEG + (s.x >> SEG_SHIFT)], 1);
        r.y = atomicAdd(&cnt[d.y * SEG + (s.y >> SEG_SHIFT)], 1);
        r.z = atomicAdd(&cnt[d.z * SEG + (s.z >> SEG_SHIFT)], 1);
        r.w = atomicAdd(&cnt[d.w * SEG + (s.w >> SEG_SHIFT)], 1);
        ((int4*)rank)[i] = r;
    }
}

// dinv from completed rowptr: deg(d) = rowptr[8d+8]-rowptr[8d].
__global__ void dinv_kernel(const int* __restrict__ rowptr, float* __restrict__ dinv, int n) {
    int i = blockIdx.x * blockDim.x + threadIdx.x;
    if (i < n) dinv[i] = rsqrtf((float)(1 + rowptr[i * SEG + SEG] - rowptr[i * SEG]));
}

// Pass 1: per-block exclusive scan of 1024-chunk -> rowptr (chunk-local), bsum.
__global__ __launch_bounds__(SCAN_B) void scan_partial_kernel(
    const int* __restrict__ cnt, int* __restrict__ rowptr,
    int* __restrict__ bsum, int n) {
    __shared__ int wsum[SCAN_B / 64 + 1];
    const int tid  = threadIdx.x;
    const int lane = tid & 63;
    const int wid  = tid >> 6;
    const int i = blockIdx.x * SCAN_B + tid;

    int v = (i < n) ? cnt[i] : 0;
    int incl = v;
#pragma unroll
    for (int off = 1; off < 64; off <<= 1) {
        int t = __shfl_up(incl, off, 64);
        if (lane >= off) incl += t;
    }
    if (lane == 63) wsum[wid] = incl;
    __syncthreads();
    if (tid == 0) {
        int run = 0;
#pragma unroll
        for (int w = 0; w < SCAN_B / 64; ++w) { int t = wsum[w]; wsum[w] = run; run += t; }
        wsum[SCAN_B / 64] = run;
        bsum[blockIdx.x] = run;
    }
    __syncthreads();
    if (i < n) rowptr[i] = incl - v + wsum[wid];
}

// Pass 2: exclusive scan of block sums, single block, nb <= 1024.
__global__ __launch_bounds__(SCAN_B) void scan_sums_kernel(int* __restrict__ bsum, int nb) {
    __shared__ int wsum[SCAN_B / 64 + 1];
    const int tid  = threadIdx.x;
    const int lane = tid & 63;
    const int wid  = tid >> 6;
    int v = (tid < nb) ? bsum[tid] : 0;
    int incl = v;
#pragma unroll
    for (int off = 1; off < 64; off <<= 1) {
        int t = __shfl_up(incl, off, 64);
        if (lane >= off) incl += t;
    }
    if (lane == 63) wsum[wid] = incl;
    __syncthreads();
    if (tid == 0) {
        int run = 0;
#pragma unroll
        for (int w = 0; w < SCAN_B / 64; ++w) { int t = wsum[w]; wsum[w] = run; run += t; }
        wsum[SCAN_B / 64] = run;
    }
    __syncthreads();
    if (tid < nb) bsum[tid] = incl - v + wsum[wid];
    if (tid == 0) bsum[nb] = wsum[SCAN_B / 64];
}

// Pass 3: add block offsets; write rowptr[n].
__global__ __launch_bounds__(SCAN_B) void scan_add_kernel(
    int* __restrict__ rowptr, const int* __restrict__ bsum, int n, int nb) {
    const int i = blockIdx.x * SCAN_B + (int)threadIdx.x;
    if (i < n) rowptr[i] += bsum[blockIdx.x];
    if (i == 0) rowptr[n] = bsum[nb];
}

// Atomic-free CSR fill (recomputes the virtual-row key).
__global__ void fill_kernel(const int* __restrict__ src, const int* __restrict__ dst,
                            const int* __restrict__ rank, const int* __restrict__ rowptr,
                            int* __restrict__ col, int E4) {
    int i = blockIdx.x * blockDim.x + threadIdx.x;
    if (i < E4) {
        int4 s = ((const int4*)src)[i];
        int4 d = ((const int4*)dst)[i];
        int4 r = ((const int4*)rank)[i];
        col[rowptr[d.x * SEG + (s.x >> SEG_SHIFT)] + r.x] = s.x;
        col[rowptr[d.y * SEG + (s.y >> SEG_SHIFT)] + r.y] = s.y;
        col[rowptr[d.z * SEG + (s.z >> SEG_SHIFT)] + r.z] = s.z;
        col[rowptr[d.w * SEG + (s.w >> SEG_SHIFT)] + r.w] = s.w;
    }
}

// Xs = x * dinv[row]   (i indexes float4s; 16 float4s per row)
__global__ void prescale_kernel(const float* __restrict__ x, const float* __restrict__ dinv,
                                float* __restrict__ xs, int nq) {
    int i = blockIdx.x * blockDim.x + threadIdx.x;
    if (i < nq) {
        float d = dinv[i >> 4];
        float4 v = ((const float4*)x)[i];
        ((float4*)xs)[i] = make_float4(v.x * d, v.y * d, v.z * d, v.w * d);
    }
}

// ---------- fused layer: gather-sum -> LDS -> GEMM -> bias/act ----------
// 16 nodes per block, 16 lanes per node (float4/lane). s_tile stride 68 breaks
// the 4-way bank conflict on the GEMM k-loop reads. Aggregated rows are
// wave-private in LDS, so the only barrier is after the W load.
#define STILE 68
__global__ __launch_bounds__(256) void layer_kernel(
    const int* __restrict__ rowptr, const int* __restrict__ col,
    const float* __restrict__ dinv, const float* __restrict__ Xs,
    const float* __restrict__ W, const float* __restrict__ bias,
    float* __restrict__ out, int n, int inter) {
    __shared__ float w_lds[FEAT * FEAT];   // [k][c]
    __shared__ float s_tile[16 * STILE];   // [r][k], padded

    const int t = threadIdx.x;
#pragma unroll
    for (int i = 0; i < 4; ++i) {
        int idx = (i * 256 + t) * 4;
        *(float4*)&w_lds[idx] = *(const float4*)&W[idx];
    }
    __syncthreads();   // W visible; nothing else needs a barrier below

    const int r  = t >> 4;       // local node 0..15
    const int c4 = t & 15;       // float4 feature group
    const int g  = blockIdx.x * 16 + r;
    if (g >= n) return;
    const int f = c4 * 4;
    const float* __restrict__ Hf = Xs + f;

    // gather raw sums (input prescaled by dinv[src]); list is segment-sorted
    float4 a0 = *(const float4*)&Hf[(size_t)g * FEAT];   // self-loop term
    float4 a1 = make_float4(0.f, 0.f, 0.f, 0.f);
    int p = rowptr[g * SEG];
    const int end = rowptr[g * SEG + SEG];
    for (; p + 4 <= end; p += 4) {
        const int s0 = col[p + 0];
        const int s1 = col[p + 1];
        const int s2 = col[p + 2];
        const int s3 = col[p + 3];
        const float4 h0 = *(const float4*)&Hf[(size_t)s0 * FEAT];
        const float4 h1 = *(const float4*)&Hf[(size_t)s1 * FEAT];
        const float4 h2 = *(const float4*)&Hf[(size_t)s2 * FEAT];
        const float4 h3 = *(const float4*)&Hf[(size_t)s3 * FEAT];
        a0.x += h0.x; a0.y += h0.y; a0.z += h0.z; a0.w += h0.w;
        a1.x += h1.x; a1.y += h1.y; a1.z += h1.z; a1.w += h1.w;
        a0.x += h2.x; a0.y += h2.y; a0.z += h2.z; a0.w += h2.w;
        a1.x += h3.x; a1.y += h3.y; a1.z += h3.z; a1.w += h3.w;
    }
    for (; p < end; ++p) {
        const int s = col[p];
        const float4 h = *(const float4*)&Hf[(size_t)s * FEAT];
        a0.x += h.x; a0.y += h.y; a0.z += h.z; a0.w += h.w;
    }
    float4 S = make_float4(a0.x + a1.x, a0.y + a1.y, a0.z + a1.z, a0.w + a1.w);
    *(float4*)&s_tile[r * STILE + f] = S;
    // no __syncthreads: wave w reads only rows 4w..4w+3, which it wrote

    // in-block GEMM: T[r][f..f+3] = sum_k S[r][k] * W[k][f..f+3]
    float4 acc = make_float4(0.f, 0.f, 0.f, 0.f);
#pragma unroll
    for (int k = 0; k < FEAT; ++k) {
        const float sv = s_tile[r * STILE + k];
        const float4 wv = *(const float4*)&w_lds[k * FEAT + f];
        acc.x += sv * wv.x; acc.y += sv * wv.y;
        acc.z += sv * wv.z; acc.w += sv * wv.w;
    }

    const float dd = dinv[g];
    const float4 bv = *(const float4*)&bias[f];
    float4 o = make_float4(acc.x * dd + bv.x, acc.y * dd + bv.y,
                           acc.z * dd + bv.z, acc.w * dd + bv.w);
    if (inter) {   // ReLU, then pre-scale for next layer's gather
        o.x = fmaxf(o.x, 0.f) * dd; o.y = fmaxf(o.y, 0.f) * dd;
        o.z = fmaxf(o.z, 0.f) * dd; o.w = fmaxf(o.w, 0.f) * dd;
    }
    *(float4*)&out[(size_t)g * FEAT + f] = o;
}

extern "C" void kernel_launch(void* const* d_in, const int* in_sizes, int n_in,
                              void* d_out, int out_size, void* d_ws, size_t ws_size,
                              hipStream_t stream) {
    const float* x  = (const float*)d_in[0];
    const int*   ei = (const int*)d_in[1];
    const float* W0 = (const float*)d_in[2];
    const float* b0 = (const float*)d_in[3];
    const float* W1 = (const float*)d_in[4];
    const float* b1 = (const float*)d_in[5];
    const float* W2 = (const float*)d_in[6];
    const float* b2 = (const float*)d_in[7];
    float* out = (float*)d_out;

    const int N = in_sizes[0] / FEAT;   // 50000
    const int E = in_sizes[1] / 2;      // 800000
    const int* src = ei;
    const int* dst = ei + E;

    const int NV = N * SEG;                         // virtual rows
    const int nbScan = (NV + SCAN_B - 1) / SCAN_B;  // 391 <= 1024

    // workspace layout
    char* w = (char*)d_ws;
    int*   cnt    = (int*)w;                 w += sizeof(int) * (size_t)NV;
    int*   rowptr = (int*)w;                 w += sizeof(int) * (size_t)(NV + 1);
    int*   bsum   = (int*)w;                 w += sizeof(int) * (size_t)(nbScan + 1);
    int*   col    = (int*)w;                 w += sizeof(int) * (size_t)E;
    float* dinv   = (float*)w;               w += sizeof(float) * (size_t)N;
    float* B1     = (float*)w;               w += sizeof(float) * (size_t)N * FEAT;
    float* B2     = (float*)w;               w += sizeof(float) * (size_t)N * FEAT;
    int*   rank   = (int*)B2;   // alias: rank dead before layer0 writes B2

    const int tB = 256;
    const int gN  = (N + tB - 1) / tB;
    const int E4  = E / 4;                    // E divisible by 4
    const int gE4 = (E4 + tB - 1) / tB;
    const int g16 = (N + 15) / 16;
    const int nq = N * FEAT / 4;
    const int gQ = (nq + tB - 1) / tB;

    // CSR build (shared by all 3 layers)
    hipMemsetAsync(cnt, 0, sizeof(int) * (size_t)NV, stream);
    deg_rank_kernel<<<gE4, tB, 0, stream>>>(src, dst, cnt, rank, E4);
    scan_partial_kernel<<<nbScan, SCAN_B, 0, stream>>>(cnt, rowptr, bsum, NV);
    scan_sums_kernel<<<1, SCAN_B, 0, stream>>>(bsum, nbScan);
    scan_add_kernel<<<nbScan, SCAN_B, 0, stream>>>(rowptr, bsum, NV, nbScan);
    dinv_kernel<<<gN, tB, 0, stream>>>(rowptr, dinv, N);
    fill_kernel<<<gE4, tB, 0, stream>>>(src, dst, rank, rowptr, col, E4);

    // prescale input: B1 = x * dinv[row]
    prescale_kernel<<<gQ, tB, 0, stream>>>(x, dinv, B1, nq);

    // fused layers
    layer_kernel<<<g16, tB, 0, stream>>>(rowptr, col, dinv, B1, W0, b0, B2, N, 1);
    layer_kernel<<<g16, tB, 0, stream>>>(rowptr, col, dinv, B2, W1, b1, B1, N, 1);
    layer_kernel<<<g16, tB, 0, stream>>>(rowptr, col, dinv, B1, W2, b2, out, N, 0);
}

// Round 7
// 252.989 us; speedup vs baseline: 8.5260x; 1.0031x over previous
//
#include <hip/hip_runtime.h>

// GCN 3-layer forward, fp32 — Round 7: flat CSR (segmentation reverted), nt
// streaming loads in the build path, dinv fused into scan, prescale fused
// into layer 0, per-layer kernel symbols for profiling.
//   agg(X@W) == agg(X)@W  =>  per layer: gather-sum -> in-block GEMM -> bias/act.
//   dinv[i] = rsqrt(1+indeg(i)); intermediate layers emit y*dinv (pre-scaled),
//   layer 0 gathers x[s]*dinv[s] on the fly.

#define FEAT 64
#define SCAN_B 1024
#define STILE 68   // s_tile stride: breaks 4-way LDS bank conflict on k-loop

typedef int   v4i __attribute__((ext_vector_type(4)));

// ---------- CSR build ----------
// degree count; atomic return value = within-row rank of edge e. Only dst needed.
__global__ void deg_rank_kernel(const int* __restrict__ dst, int* __restrict__ cnt,
                                int* __restrict__ rank, int E4) {
    int i = blockIdx.x * blockDim.x + threadIdx.x;
    if (i < E4) {
        v4i d = __builtin_nontemporal_load(((const v4i*)dst) + i);
        v4i r;
        r[0] = atomicAdd(&cnt[d[0]], 1);
        r[1] = atomicAdd(&cnt[d[1]], 1);
        r[2] = atomicAdd(&cnt[d[2]], 1);
        r[3] = atomicAdd(&cnt[d[3]], 1);
        __builtin_nontemporal_store(r, ((v4i*)rank) + i);
    }
}

// Pass 1: per-block exclusive scan of 1024-chunk -> rowptr (chunk-local), bsum.
// Also emits dinv[i] = rsqrt(1+cnt[i]) for free.
__global__ __launch_bounds__(SCAN_B) void scan_partial_kernel(
    const int* __restrict__ cnt, int* __restrict__ rowptr,
    int* __restrict__ bsum, float* __restrict__ dinv, int n) {
    __shared__ int wsum[SCAN_B / 64 + 1];
    const int tid  = threadIdx.x;
    const int lane = tid & 63;
    const int wid  = tid >> 6;
    const int i = blockIdx.x * SCAN_B + tid;

    int v = (i < n) ? cnt[i] : 0;
    if (i < n) dinv[i] = rsqrtf((float)(1 + v));
    int incl = v;
#pragma unroll
    for (int off = 1; off < 64; off <<= 1) {
        int t = __shfl_up(incl, off, 64);
        if (lane >= off) incl += t;
    }
    if (lane == 63) wsum[wid] = incl;
    __syncthreads();
    if (tid == 0) {
        int run = 0;
#pragma unroll
        for (int w = 0; w < SCAN_B / 64; ++w) { int t = wsum[w]; wsum[w] = run; run += t; }
        wsum[SCAN_B / 64] = run;
        bsum[blockIdx.x] = run;
    }
    __syncthreads();
    if (i < n) rowptr[i] = incl - v + wsum[wid];
}

// Pass 2: exclusive scan of block sums, single block, nb <= 1024.
__global__ __launch_bounds__(SCAN_B) void scan_sums_kernel(int* __restrict__ bsum, int nb) {
    __shared__ int wsum[SCAN_B / 64 + 1];
    const int tid  = threadIdx.x;
    const int lane = tid & 63;
    const int wid  = tid >> 6;
    int v = (tid < nb) ? bsum[tid] : 0;
    int incl = v;
#pragma unroll
    for (int off = 1; off < 64; off <<= 1) {
        int t = __shfl_up(incl, off, 64);
        if (lane >= off) incl += t;
    }
    if (lane == 63) wsum[wid] = incl;
    __syncthreads();
    if (tid == 0) {
        int run = 0;
#pragma unroll
        for (int w = 0; w < SCAN_B / 64; ++w) { int t = wsum[w]; wsum[w] = run; run += t; }
        wsum[SCAN_B / 64] = run;
    }
    __syncthreads();
    if (tid < nb) bsum[tid] = incl - v + wsum[wid];
    if (tid == 0) bsum[nb] = wsum[SCAN_B / 64];
}

// Pass 3: add block offsets; write rowptr[n].
__global__ __launch_bounds__(SCAN_B) void scan_add_kernel(
    int* __restrict__ rowptr, const int* __restrict__ bsum, int n, int nb) {
    const int i = blockIdx.x * SCAN_B + (int)threadIdx.x;
    if (i < n) rowptr[i] += bsum[blockIdx.x];
    if (i == 0) rowptr[n] = bsum[nb];
}

// Atomic-free CSR fill; streaming inputs bypass-cached so col stays L2-resident.
__global__ void fill_kernel(const int* __restrict__ src, const int* __restrict__ dst,
                            const int* __restrict__ rank, const int* __restrict__ rowptr,
                            int* __restrict__ col, int E4) {
    int i = blockIdx.x * blockDim.x + threadIdx.x;
    if (i < E4) {
        v4i s = __builtin_nontemporal_load(((const v4i*)src) + i);
        v4i d = __builtin_nontemporal_load(((const v4i*)dst) + i);
        v4i r = __builtin_nontemporal_load(((const v4i*)rank) + i);
        col[rowptr[d[0]] + r[0]] = s[0];
        col[rowptr[d[1]] + r[1]] = s[1];
        col[rowptr[d[2]] + r[2]] = s[2];
        col[rowptr[d[3]] + r[3]] = s[3];
    }
}

// ---------- fused layer: gather-sum -> LDS -> GEMM -> bias/act ----------
// 16 nodes per block, 16 lanes per node (float4/lane). Aggregated rows are
// wave-private in LDS, so the only barrier is after the W load.
// PRE: input is unscaled (layer 0) -> multiply each gathered row by dinv[s].
// INTER: ReLU + pre-scale output by dinv for the next layer's gather.
template<int INTER, int PRE>
__global__ __launch_bounds__(256) void layer_kernel(
    const int* __restrict__ rowptr, const int* __restrict__ col,
    const float* __restrict__ dinv, const float* __restrict__ Xs,
    const float* __restrict__ W, const float* __restrict__ bias,
    float* __restrict__ out, int n) {
    __shared__ float w_lds[FEAT * FEAT];   // [k][c]
    __shared__ float s_tile[16 * STILE];   // [r][k], padded

    const int t = threadIdx.x;
#pragma unroll
    for (int i = 0; i < 4; ++i) {
        int idx = (i * 256 + t) * 4;
        *(float4*)&w_lds[idx] = *(const float4*)&W[idx];
    }
    __syncthreads();   // W visible; nothing else needs a barrier below

    const int r  = t >> 4;       // local node 0..15
    const int c4 = t & 15;       // float4 feature group
    const int g  = blockIdx.x * 16 + r;
    if (g >= n) return;
    const int f = c4 * 4;
    const float* __restrict__ Hf = Xs + f;

    const float dg = dinv[g];

    // self-loop term
    float4 a0 = *(const float4*)&Hf[(size_t)g * FEAT];
    if (PRE) { a0.x *= dg; a0.y *= dg; a0.z *= dg; a0.w *= dg; }
    float4 a1 = make_float4(0.f, 0.f, 0.f, 0.f);

    int p = rowptr[g];
    const int end = rowptr[g + 1];
    for (; p + 4 <= end; p += 4) {
        const int s0 = col[p + 0];
        const int s1 = col[p + 1];
        const int s2 = col[p + 2];
        const int s3 = col[p + 3];
        float4 h0 = *(const float4*)&Hf[(size_t)s0 * FEAT];
        float4 h1 = *(const float4*)&Hf[(size_t)s1 * FEAT];
        float4 h2 = *(const float4*)&Hf[(size_t)s2 * FEAT];
        float4 h3 = *(const float4*)&Hf[(size_t)s3 * FEAT];
        if (PRE) {
            const float d0 = dinv[s0], d1 = dinv[s1], d2 = dinv[s2], d3 = dinv[s3];
            h0.x *= d0; h0.y *= d0; h0.z *= d0; h0.w *= d0;
            h1.x *= d1; h1.y *= d1; h1.z *= d1; h1.w *= d1;
            h2.x *= d2; h2.y *= d2; h2.z *= d2; h2.w *= d2;
            h3.x *= d3; h3.y *= d3; h3.z *= d3; h3.w *= d3;
        }
        a0.x += h0.x; a0.y += h0.y; a0.z += h0.z; a0.w += h0.w;
        a1.x += h1.x; a1.y += h1.y; a1.z += h1.z; a1.w += h1.w;
        a0.x += h2.x; a0.y += h2.y; a0.z += h2.z; a0.w += h2.w;
        a1.x += h3.x; a1.y += h3.y; a1.z += h3.z; a1.w += h3.w;
    }
    for (; p < end; ++p) {
        const int s = col[p];
        float4 h = *(const float4*)&Hf[(size_t)s * FEAT];
        if (PRE) {
            const float d = dinv[s];
            h.x *= d; h.y *= d; h.z *= d; h.w *= d;
        }
        a0.x += h.x; a0.y += h.y; a0.z += h.z; a0.w += h.w;
    }
    float4 S = make_float4(a0.x + a1.x, a0.y + a1.y, a0.z + a1.z, a0.w + a1.w);
    *(float4*)&s_tile[r * STILE + f] = S;
    // no __syncthreads: wave w reads only rows 4w..4w+3, which it wrote

    // in-block GEMM: T[r][f..f+3] = sum_k S[r][k] * W[k][f..f+3]
    float4 acc = make_float4(0.f, 0.f, 0.f, 0.f);
#pragma unroll
    for (int k = 0; k < FEAT; ++k) {
        const float sv = s_tile[r * STILE + k];
        const float4 wv = *(const float4*)&w_lds[k * FEAT + f];
        acc.x += sv * wv.x; acc.y += sv * wv.y;
        acc.z += sv * wv.z; acc.w += sv * wv.w;
    }

    const float4 bv = *(const float4*)&bias[f];
    float4 o = make_float4(acc.x * dg + bv.x, acc.y * dg + bv.y,
                           acc.z * dg + bv.z, acc.w * dg + bv.w);
    if (INTER) {   // ReLU, then pre-scale for next layer's gather
        o.x = fmaxf(o.x, 0.f) * dg; o.y = fmaxf(o.y, 0.f) * dg;
        o.z = fmaxf(o.z, 0.f) * dg; o.w = fmaxf(o.w, 0.f) * dg;
    }
    *(float4*)&out[(size_t)g * FEAT + f] = o;
}

extern "C" void kernel_launch(void* const* d_in, const int* in_sizes, int n_in,
                              void* d_out, int out_size, void* d_ws, size_t ws_size,
                              hipStream_t stream) {
    const float* x  = (const float*)d_in[0];
    const int*   ei = (const int*)d_in[1];
    const float* W0 = (const float*)d_in[2];
    const float* b0 = (const float*)d_in[3];
    const float* W1 = (const float*)d_in[4];
    const float* b1 = (const float*)d_in[5];
    const float* W2 = (const float*)d_in[6];
    const float* b2 = (const float*)d_in[7];
    float* out = (float*)d_out;

    const int N = in_sizes[0] / FEAT;   // 50000
    const int E = in_sizes[1] / 2;      // 800000 (divisible by 4)
    const int* src = ei;
    const int* dst = ei + E;

    const int nbScan = (N + SCAN_B - 1) / SCAN_B;   // 49

    // workspace layout
    char* w = (char*)d_ws;
    int*   cnt    = (int*)w;                 w += sizeof(int) * (size_t)N;
    int*   rowptr = (int*)w;                 w += sizeof(int) * (size_t)(N + 1);
    int*   bsum   = (int*)w;                 w += sizeof(int) * (size_t)(nbScan + 1);
    int*   col    = (int*)w;                 w += sizeof(int) * (size_t)E;
    float* dinv   = (float*)w;               w += sizeof(float) * (size_t)N;
    float* B1     = (float*)w;               w += sizeof(float) * (size_t)N * FEAT;
    float* B2     = (float*)w;               w += sizeof(float) * (size_t)N * FEAT;
    int*   rank   = (int*)B2;   // alias: rank dead before layer0 writes B2

    const int tB = 256;
    const int E4  = E / 4;
    const int gE4 = (E4 + tB - 1) / tB;
    const int g16 = (N + 15) / 16;

    // CSR build (shared by all 3 layers)
    hipMemsetAsync(cnt, 0, sizeof(int) * (size_t)N, stream);
    deg_rank_kernel<<<gE4, tB, 0, stream>>>(dst, cnt, rank, E4);
    scan_partial_kernel<<<nbScan, SCAN_B, 0, stream>>>(cnt, rowptr, bsum, dinv, N);
    scan_sums_kernel<<<1, SCAN_B, 0, stream>>>(bsum, nbScan);
    scan_add_kernel<<<nbScan, SCAN_B, 0, stream>>>(rowptr, bsum, N, nbScan);
    fill_kernel<<<gE4, tB, 0, stream>>>(src, dst, rank, rowptr, col, E4);

    // fused layers (layer 0 prescales its gather on the fly)
    layer_kernel<1, 1><<<g16, tB, 0, stream>>>(rowptr, col, dinv, x,  W0, b0, B2, N);
    layer_kernel<1, 0><<<g16, tB, 0, stream>>>(rowptr, col, dinv, B2, W1, b1, B1, N);
    layer_kernel<0, 0><<<g16, tB, 0, stream>>>(rowptr, col, dinv, B1, W2, b2, out, N);
}